// Round 5
// baseline (952.471 us; speedup 1.0000x reference)
//
#include <hip/hip_runtime.h>
#include <hip/hip_bf16.h>

#define NEG_SLOPE 0.2f

using bf16 = __hip_bfloat16;
using short8  = __attribute__((ext_vector_type(8))) short;
using float4v = __attribute__((ext_vector_type(4))) float;

__device__ __forceinline__ float tof(bf16 v) { return __bfloat162float(v); }
__device__ __forceinline__ float tof(float v) { return v; }
__device__ __forceinline__ void store_val(bf16* p, float v) { *p = __float2bfloat16(v); }
__device__ __forceinline__ void store_val(float* p, float v) { *p = v; }

__device__ __forceinline__ float2 load2(const bf16* p) {
    unsigned int u = *(const unsigned int*)p;
    float2 r;
    r.x = __uint_as_float((u & 0xffffu) << 16);
    r.y = __uint_as_float(u & 0xffff0000u);
    return r;
}
__device__ __forceinline__ float2 load2(const float* p) { return *(const float2*)p; }

// true if first 128 half-words of p look like fp32 bit patterns (not bf16 ~N(0,1))
__device__ __forceinline__ int detect_fp32(const void* p_) {
    const unsigned short* p = (const unsigned short*)p_;
    int f32 = 0;
    for (int i = 0; i < 128; ++i) {
        float v = __uint_as_float(((unsigned int)p[i]) << 16);
        if (!(fabsf(v) < 100.f)) f32 = 1;  // catches NaN too
    }
    return f32;
}

// unpack uint4 (8 bf16) -> 8 floats
__device__ __forceinline__ void unpack8(uint4 raw, float* o) {
    const unsigned short* hb = (const unsigned short*)&raw;
#pragma unroll
    for (int k = 0; k < 8; ++k) o[k] = __uint_as_float(((unsigned int)hb[k]) << 16);
}

// =====================================================================
// T: transpose weights into [N][K] bf16 layouts in workspace
//   w0 [4][256][128] -> wt0 [4][128][256]
//   w1 [4][512][128] -> wt1 [4][128][512]
//   fcw [512][256]   -> fcwt [256][512]
// =====================================================================
__global__ __launch_bounds__(256) void transpose_weights(
    const bf16* __restrict__ w0, const bf16* __restrict__ w1,
    const bf16* __restrict__ fcw, bf16* __restrict__ wt0,
    bf16* __restrict__ wt1, bf16* __restrict__ fcwt)
{
    __shared__ int fp32flag;
    if (threadIdx.x == 0) fp32flag = detect_fp32(w0);
    __syncthreads();
    if (fp32flag) return;

    int i = blockIdx.x * 256 + threadIdx.x;
    const int E0 = 4 * 256 * 128;   // 131072
    const int E1 = 4 * 512 * 128;   // 262144
    const int E2 = 512 * 256;       // 131072
    if (i < E0) {
        int b = i >> 15, r = (i & 32767) >> 7, c = i & 127;
        wt0[((size_t)b * 128 + c) * 256 + r] = w0[i];
    } else if (i < E0 + E1) {
        int j = i - E0;
        int b = j >> 16, r = (j & 65535) >> 7, c = j & 127;
        wt1[((size_t)b * 128 + c) * 512 + r] = w1[j];
    } else if (i < E0 + E1 + E2) {
        int k = i - E0 - E1;
        int r = k >> 8, c = k & 255;
        fcwt[(size_t)c * 512 + r] = fcw[k];
    }
}

// =====================================================================
// K1: layer-0 attention + aggregate. One block per node (n < B: root
// level, NS=11; else level-1 node, NS=26). Writes xbar0 [4][NB][256] bf16.
// =====================================================================
__global__ __launch_bounds__(256) void gat_l0_attn(
    const bf16* __restrict__ x0, const bf16* __restrict__ x1,
    const bf16* __restrict__ x2, const bf16* __restrict__ a0s,
    const bf16* __restrict__ a0n, bf16* __restrict__ xbar0, int B, int NB)
{
    const int n = blockIdx.x;
    const int tid = threadIdx.x;

    __shared__ float xs[26 * 260];
    __shared__ float asl[4 * 256];
    __shared__ float anl[4 * 256];
    __shared__ float attnw[4][26];
    __shared__ float lsf[4];
    __shared__ int fp32flag;

    if (tid == 0) fp32flag = detect_fp32(x0);
    __syncthreads();
    if (fp32flag) return;

    // stage attention vectors (4*256 each) to LDS as fp32
    if (tid < 128) {
        int h = tid >> 5, c8 = (tid & 31) * 8;
        unpack8(*(const uint4*)(a0s + h * 256 + c8), &asl[h * 256 + c8]);
        unpack8(*(const uint4*)(a0n + h * 256 + c8), &anl[h * 256 + c8]);
    }

    int NS;
    const bf16 *self, *neigh;
    if (n < B) { NS = 11; self = x0 + (size_t)n * 256; neigh = x1 + (size_t)n * 2560; }
    else { int m = n - B; NS = 26; self = x1 + (size_t)m * 256; neigh = x2 + (size_t)m * 25 * 256; }

    // stage x_all rows to LDS fp32 (row stride 260)
    for (int i = tid; i < NS * 32; i += 256) {
        int s = i >> 5, c8 = (i & 31) * 8;
        const bf16* src = (s == 0) ? (self + c8) : (neigh + (size_t)(s - 1) * 256 + c8);
        unpack8(*(const uint4*)src, &xs[s * 260 + c8]);
    }
    __syncthreads();

    // logits: 2 threads per (sample,head) unit
    {
        int NU = (NS + 1) * 4;
        int u = tid >> 1;
        float acc = 0.f;
        if (u < NU) {
            int s = u >> 2, h = u & 3;
            const float* av = ((s < NS) ? anl : asl) + h * 256;
            const float* xrow = xs + (s < NS ? s : 0) * 260;
            int f0 = (tid & 1) * 128;
            float a0 = 0.f, a1 = 0.f, a2 = 0.f, a3 = 0.f;
            for (int f = f0; f < f0 + 128; f += 4) {
                float4 xv = *(const float4*)&xrow[f];
                float4 avv = *(const float4*)&av[f];
                a0 += xv.x * avv.x; a1 += xv.y * avv.y;
                a2 += xv.z * avv.z; a3 += xv.w * avv.w;
            }
            acc = (a0 + a1) + (a2 + a3);
        }
        float other = __shfl_xor(acc, 1);
        if (u < NU && (tid & 1) == 0) {
            float tot = acc + other;
            int s = u >> 2, h = u & 3;
            if (s < NS) attnw[h][s] = tot;
            else        lsf[h] = tot;
        }
    }
    __syncthreads();

    // leaky_relu + softmax (4 threads, LDS-resident, no private arrays)
    if (tid < 4) {
        int h = tid;
        float ls = lsf[h];
        float m = -1e30f;
        for (int s = 0; s < NS; ++s) {
            float x = ls + attnw[h][s];
            x = (x > 0.f) ? x : NEG_SLOPE * x;
            m = fmaxf(m, x);
        }
        float sum = 0.f;
        for (int s = 0; s < NS; ++s) {
            float x = ls + attnw[h][s];
            x = (x > 0.f) ? x : NEG_SLOPE * x;
            float e = __expf(x - m);
            attnw[h][s] = e;
            sum += e;
        }
        float inv = 1.f / sum;
        for (int s = 0; s < NS; ++s) attnw[h][s] *= inv;
    }
    __syncthreads();

    // aggregate + write xbar0 (bf16)
    {
        float a0 = 0.f, a1 = 0.f, a2 = 0.f, a3 = 0.f;
        for (int s = 0; s < NS; ++s) {
            float xv = xs[s * 260 + tid];
            a0 += attnw[0][s] * xv;
            a1 += attnw[1][s] * xv;
            a2 += attnw[2][s] * xv;
            a3 += attnw[3][s] * xv;
        }
        size_t base = (size_t)n * 256 + tid;
        size_t hstr = (size_t)NB * 256;
        xbar0[base]            = __float2bfloat16(a0);
        xbar0[base + hstr]     = __float2bfloat16(a1);
        xbar0[base + 2 * hstr] = __float2bfloat16(a2);
        xbar0[base + 3 * hstr] = __float2bfloat16(a3);
    }
}

// =====================================================================
// MFMA GEMM: C[M x Ntot] (+head offset) = A[Z][M][K](bf16) * Bt[Z][N][K](bf16)^T
// BM=64 BN=128 BK=64, 256 threads = 4 waves (wave w: 16-row strip).
// 16x16x32 bf16 MFMA; layouts verified (m89/m91/m120):
//   A-frag:  A[m=lane&15][k=(lane>>4)*8+j]
//   B-frag:  B[n=lane&15][k=(lane>>4)*8+j]  (from Bt rows)
//   C/D:     col=lane&15, row=(lane>>4)*4+reg
// =====================================================================
template <int K>
__global__ __launch_bounds__(256) void mfma_gemm(
    const bf16* __restrict__ A, const bf16* __restrict__ Bt, void* __restrict__ C,
    int c_is_bf16, size_t hsA, size_t hsB, int ldC, int hsC,
    const bf16* __restrict__ probe)
{
    __shared__ short As[64 * 72];
    __shared__ short Bs[128 * 72];
    __shared__ int fp32flag;

    const int tid = threadIdx.x;
    if (tid == 0) fp32flag = detect_fp32(probe);
    __syncthreads();
    if (fp32flag) return;

    const int z = blockIdx.z;
    const int mbase = blockIdx.x * 64;
    const int nbase = blockIdx.y * 128;

    const bf16* Ab  = A  + hsA * z + (size_t)mbase * K;
    const bf16* Btb = Bt + hsB * z + (size_t)nbase * K;

    const int w = tid >> 6;          // wave id 0..3
    const int lane = tid & 63;
    const int ln = lane & 15;
    const int quad = lane >> 4;

    float4v acc[8];
#pragma unroll
    for (int t = 0; t < 8; ++t)
#pragma unroll
        for (int j = 0; j < 4; ++j) acc[t][j] = 0.f;

    for (int k0 = 0; k0 < K; k0 += 64) {
        // stage A tile: 64x64 = 512 vec8 groups
#pragma unroll
        for (int it = 0; it < 2; ++it) {
            int g = tid + it * 256;
            int r = g >> 3, c8 = (g & 7) * 8;
            uint4 v = *(const uint4*)(Ab + (size_t)r * K + k0 + c8);
            *(uint4*)&As[r * 72 + c8] = v;
        }
        // stage B tile: 128x64 = 1024 vec8 groups
#pragma unroll
        for (int it = 0; it < 4; ++it) {
            int g = tid + it * 256;
            int r = g >> 3, c8 = (g & 7) * 8;
            uint4 v = *(const uint4*)(Btb + (size_t)r * K + k0 + c8);
            *(uint4*)&Bs[r * 72 + c8] = v;
        }
        __syncthreads();

        int m_l = (w << 4) + ln;
#pragma unroll
        for (int ks = 0; ks < 64; ks += 32) {
            short8 af = *(const short8*)&As[m_l * 72 + ks + (quad << 3)];
#pragma unroll
            for (int t = 0; t < 8; ++t) {
                short8 bfv = *(const short8*)&Bs[(t * 16 + ln) * 72 + ks + (quad << 3)];
                acc[t] = __builtin_amdgcn_mfma_f32_16x16x32_bf16(af, bfv, acc[t], 0, 0, 0);
            }
        }
        __syncthreads();
    }

    // epilogue
    const int coff = hsC * z + nbase;
#pragma unroll
    for (int t = 0; t < 8; ++t) {
#pragma unroll
        for (int reg = 0; reg < 4; ++reg) {
            int row = mbase + (w << 4) + (quad << 2) + reg;
            int col = coff + t * 16 + ln;
            if (c_is_bf16)
                ((bf16*)C)[(size_t)row * ldC + col] = __float2bfloat16(acc[t][reg]);
            else
                ((float*)C)[(size_t)row * ldC + col] = acc[t][reg];
        }
    }
}

// =====================================================================
// K3: layer-1 attention + aggregate. One block per root. Reads h_all
// (fp32 [NB][512]; row b = root, rows B+b*10+p = children). Writes
// xbar1 [4][B][512] bf16.
// =====================================================================
__global__ __launch_bounds__(256) void gat_l1_attn(
    const float* __restrict__ h_all, const bf16* __restrict__ a1s,
    const bf16* __restrict__ a1n, bf16* __restrict__ xbar1, int B,
    const bf16* __restrict__ probe)
{
    const int b = blockIdx.x;
    const int tid = threadIdx.x;

    __shared__ float hs[11 * 516];
    __shared__ float asl[4 * 512];
    __shared__ float anl[4 * 512];
    __shared__ float attnw[4][26];
    __shared__ float lsf[4];
    __shared__ int fp32flag;

    if (tid == 0) fp32flag = detect_fp32(probe);
    __syncthreads();
    if (fp32flag) return;

    // stage a-vectors: 4*512/8 = 256 groups
    {
        int h = tid >> 6, c8 = (tid & 63) * 8;
        unpack8(*(const uint4*)(a1s + h * 512 + c8), &asl[h * 512 + c8]);
        unpack8(*(const uint4*)(a1n + h * 512 + c8), &anl[h * 512 + c8]);
    }

    // stage 11 rows of 512 fp32 (stride 516): 1408 float4 groups
    for (int i = tid; i < 1408; i += 256) {
        int s = i >> 7, c4 = (i & 127) * 4;
        const float* src = (s == 0) ? (h_all + (size_t)b * 512 + c4)
                                    : (h_all + (size_t)(B + b * 10 + s - 1) * 512 + c4);
        *(float4*)&hs[s * 516 + c4] = *(const float4*)src;
    }
    __syncthreads();

    // logits: NS=11, NU=48, 2 threads/unit
    {
        int u = tid >> 1;
        float acc = 0.f;
        if (u < 48) {
            int s = u >> 2, h = u & 3;
            const float* av = ((s < 11) ? anl : asl) + h * 512;
            const float* xrow = hs + (s < 11 ? s : 0) * 516;
            int f0 = (tid & 1) * 256;
            float a0 = 0.f, a1 = 0.f, a2 = 0.f, a3 = 0.f;
            for (int f = f0; f < f0 + 256; f += 4) {
                float4 xv = *(const float4*)&xrow[f];
                float4 avv = *(const float4*)&av[f];
                a0 += xv.x * avv.x; a1 += xv.y * avv.y;
                a2 += xv.z * avv.z; a3 += xv.w * avv.w;
            }
            acc = (a0 + a1) + (a2 + a3);
        }
        float other = __shfl_xor(acc, 1);
        if (u < 48 && (tid & 1) == 0) {
            float tot = acc + other;
            int s = u >> 2, h = u & 3;
            if (s < 11) attnw[h][s] = tot;
            else        lsf[h] = tot;
        }
    }
    __syncthreads();

    if (tid < 4) {
        int h = tid;
        float ls = lsf[h];
        float m = -1e30f;
        for (int s = 0; s < 11; ++s) {
            float x = ls + attnw[h][s];
            x = (x > 0.f) ? x : NEG_SLOPE * x;
            m = fmaxf(m, x);
        }
        float sum = 0.f;
        for (int s = 0; s < 11; ++s) {
            float x = ls + attnw[h][s];
            x = (x > 0.f) ? x : NEG_SLOPE * x;
            float e = __expf(x - m);
            attnw[h][s] = e;
            sum += e;
        }
        float inv = 1.f / sum;
        for (int s = 0; s < 11; ++s) attnw[h][s] *= inv;
    }
    __syncthreads();

    // aggregate (FCH=2) + write xbar1 bf16
    {
        float a[4][2];
#pragma unroll
        for (int h = 0; h < 4; ++h) { a[h][0] = 0.f; a[h][1] = 0.f; }
        for (int s = 0; s < 11; ++s) {
            float x0v = hs[s * 516 + tid];
            float x1v = hs[s * 516 + tid + 256];
            float w0 = attnw[0][s], w1 = attnw[1][s], w2 = attnw[2][s], w3 = attnw[3][s];
            a[0][0] += w0 * x0v; a[0][1] += w0 * x1v;
            a[1][0] += w1 * x0v; a[1][1] += w1 * x1v;
            a[2][0] += w2 * x0v; a[2][1] += w2 * x1v;
            a[3][0] += w3 * x0v; a[3][1] += w3 * x1v;
        }
        size_t hstr = (size_t)B * 512;
        size_t base = (size_t)b * 512 + tid;
#pragma unroll
        for (int h = 0; h < 4; ++h) {
            xbar1[h * hstr + base]       = __float2bfloat16(a[h][0]);
            xbar1[h * hstr + base + 256] = __float2bfloat16(a[h][1]);
        }
    }
}

// =====================================================================
// Tier-1/2 fallbacks (round-3/4 proven kernels) + fp32 safety net
// =====================================================================
template <typename T, int F, int NS, int FP>
__device__ __forceinline__ void stage(float* xs, const T* self, const T* neigh, int tid) {
    constexpr int V = 16 / sizeof(T);
    constexpr int TOT = NS * F / V;
    for (int i = tid; i < TOT; i += 256) {
        int e = i * V;
        int s = e / F, f = e % F;
        const T* src = (s == 0) ? (self + f) : (neigh + (size_t)(s - 1) * F + f);
        uint4 raw = *(const uint4*)src;
        const T* hv = (const T*)&raw;
        float* dst = &xs[s * FP + f];
#pragma unroll
        for (int k = 0; k < V; ++k) dst[k] = tof(hv[k]);
    }
}

template <typename T, int F, int NS, int FP>
__device__ __forceinline__ void attention(const float* xs, const T* a_self,
                                          const T* a_neigh, float (*attn)[26],
                                          float* lsf, int tid) {
    constexpr int NU = (NS + 1) * 4;
    constexpr int HL = F / 2;
    int u = tid >> 1;
    float acc = 0.f;
    if (u < NU) {
        int s = u >> 2, h = u & 3;
        const T* a = (s < NS) ? (a_neigh + (size_t)h * F) : (a_self + (size_t)h * F);
        const float* xrow = xs + (size_t)(s < NS ? s : 0) * FP;
        int f0 = (tid & 1) * HL;
        float a0 = 0.f, a1 = 0.f, a2 = 0.f, a3 = 0.f;
        for (int f = f0; f < f0 + HL; f += 4) {
            a0 += xrow[f + 0] * tof(a[f + 0]);
            a1 += xrow[f + 1] * tof(a[f + 1]);
            a2 += xrow[f + 2] * tof(a[f + 2]);
            a3 += xrow[f + 3] * tof(a[f + 3]);
        }
        acc = (a0 + a1) + (a2 + a3);
    }
    float other = __shfl_xor(acc, 1);
    if (u < NU && (tid & 1) == 0) {
        float tot = acc + other;
        int s = u >> 2, h = u & 3;
        if (s < NS) attn[h][s] = tot;
        else        lsf[h] = tot;
    }
    __syncthreads();
    if (tid < 4) {
        int h = tid;
        float ls = lsf[h];
        float v[NS];
        float m = -1e30f;
#pragma unroll
        for (int s = 0; s < NS; ++s) {
            float x = ls + attn[h][s];
            x = (x > 0.f) ? x : NEG_SLOPE * x;
            v[s] = x;
            m = fmaxf(m, x);
        }
        float sum = 0.f;
#pragma unroll
        for (int s = 0; s < NS; ++s) { float e = __expf(v[s] - m); v[s] = e; sum += e; }
        float inv = 1.f / sum;
#pragma unroll
        for (int s = 0; s < NS; ++s) attn[h][s] = v[s] * inv;
    }
    __syncthreads();
}

template <int F, int NS, int FP>
__device__ __forceinline__ void aggregate(const float* xs, const float (*attn)[26],
                                          float* xbar, int tid) {
    constexpr int FCH = F / 256;
    float acc[4][FCH];
#pragma unroll
    for (int h = 0; h < 4; ++h)
#pragma unroll
        for (int c = 0; c < FCH; ++c) acc[h][c] = 0.f;
    for (int s = 0; s < NS; ++s) {
        float w0 = attn[0][s], w1 = attn[1][s], w2 = attn[2][s], w3 = attn[3][s];
#pragma unroll
        for (int c = 0; c < FCH; ++c) {
            float xv = xs[(size_t)s * FP + tid + c * 256];
            acc[0][c] += w0 * xv;
            acc[1][c] += w1 * xv;
            acc[2][c] += w2 * xv;
            acc[3][c] += w3 * xv;
        }
    }
#pragma unroll
    for (int c = 0; c < FCH; ++c)
#pragma unroll
        for (int h = 0; h < 4; ++h)
            xbar[h * F + tid + c * 256] = acc[h][c];
}

template <typename T, int F>
__device__ __forceinline__ float2 transform_pair(const float* xbar, const T* w, int tid) {
    int h = tid >> 6;
    int d0 = (tid & 63) * 2;
    const T* wp = w + ((size_t)h * F) * 128 + d0;
    const float* xb = xbar + (size_t)h * F;
    float r0 = 0.f, r1 = 0.f;
    for (int f = 0; f < F; ++f) {
        float xv = xb[f];
        float2 wv = load2(wp + (size_t)f * 128);
        r0 += xv * wv.x;
        r1 += xv * wv.y;
    }
    return make_float2(r0, r1);
}

template <typename T, int NS>
__device__ __forceinline__ void layer0_node(
    const T* self, const T* neigh, const T* w0, const T* a0s, const T* a0n,
    float* h_ws, float* xs, float* xbar, float (*attn)[26], float* lsf, int tid)
{
    stage<T, 256, NS, 260>(xs, self, neigh, tid);
    __syncthreads();
    attention<T, 256, NS, 260>(xs, a0s, a0n, attn, lsf, tid);
    aggregate<256, NS, 260>(xs, attn, xbar, tid);
    __syncthreads();
    float2 r = transform_pair<T, 256>(xbar, w0, tid);
    int h = tid >> 6, d0 = (tid & 63) * 2;
    *(float2*)&h_ws[h * 128 + d0] = r;
}

__global__ __launch_bounds__(256) void gat_layer0(
    const void* x0, const void* x1, const void* x2, const void* w0,
    const void* a0s, const void* a0n, float* h0_ws, float* h1_ws, int B)
{
    const int n = blockIdx.x;
    const int tid = threadIdx.x;

    __shared__ float xs[26 * 260];
    __shared__ float xbar[4 * 256];
    __shared__ float attn[4][26];
    __shared__ float lsf[4];
    __shared__ int is_fp32;

    if (tid == 0) is_fp32 = detect_fp32(x0);
    __syncthreads();

    if (!is_fp32) {
        const bf16* X0 = (const bf16*)x0; const bf16* X1 = (const bf16*)x1;
        const bf16* X2 = (const bf16*)x2; const bf16* W0 = (const bf16*)w0;
        const bf16* AS = (const bf16*)a0s; const bf16* AN = (const bf16*)a0n;
        if (n < B) {
            layer0_node<bf16, 11>(X0 + (size_t)n * 256, X1 + (size_t)n * 2560,
                                  W0, AS, AN, h0_ws + (size_t)n * 512,
                                  xs, xbar, attn, lsf, tid);
        } else {
            int m = n - B, b = m / 10, p = m % 10;
            layer0_node<bf16, 26>(X1 + ((size_t)b * 10 + p) * 256,
                                  X2 + ((size_t)b * 250 + (size_t)p * 25) * 256,
                                  W0, AS, AN, h1_ws + (size_t)m * 512,
                                  xs, xbar, attn, lsf, tid);
        }
    } else {
        const float* X0 = (const float*)x0; const float* X1 = (const float*)x1;
        const float* X2 = (const float*)x2; const float* W0 = (const float*)w0;
        const float* AS = (const float*)a0s; const float* AN = (const float*)a0n;
        if (n < B) {
            layer0_node<float, 11>(X0 + (size_t)n * 256, X1 + (size_t)n * 2560,
                                   W0, AS, AN, h0_ws + (size_t)n * 512,
                                   xs, xbar, attn, lsf, tid);
        } else {
            int m = n - B, b = m / 10, p = m % 10;
            layer0_node<float, 26>(X1 + ((size_t)b * 10 + p) * 256,
                                   X2 + ((size_t)b * 250 + (size_t)p * 25) * 256,
                                   W0, AS, AN, h1_ws + (size_t)m * 512,
                                   xs, xbar, attn, lsf, tid);
        }
    }
}

template <typename T>
__device__ __forceinline__ void layer1_body(
    const float* h0row, const float* h1rows, const T* w1, const T* a1s,
    const T* a1n, const T* fcw, T* outp, float* hs, float* xbar,
    float (*attn)[26], float* lsf, float* hroot, int tid)
{
    for (int i = tid; i < 11 * 512 / 4; i += 256) {
        int e = i * 4;
        int s = e / 512, f = e % 512;
        const float* src = (s == 0) ? (h0row + f) : (h1rows + (size_t)(s - 1) * 512 + f);
        float4 v = *(const float4*)src;
        float* dst = &hs[s * 516 + f];
        dst[0] = v.x; dst[1] = v.y; dst[2] = v.z; dst[3] = v.w;
    }
    __syncthreads();
    attention<T, 512, 11, 516>(hs, a1s, a1n, attn, lsf, tid);
    aggregate<512, 11, 516>(hs, attn, xbar, tid);
    __syncthreads();
    float2 r = transform_pair<T, 512>(xbar, w1, tid);
    int h = tid >> 6, d0 = (tid & 63) * 2;
    hroot[h * 128 + d0] = r.x;
    hroot[h * 128 + d0 + 1] = r.y;
    __syncthreads();
    const T* fp = fcw + tid;
    float a0 = 0.f, a1 = 0.f, a2 = 0.f, a3 = 0.f;
    for (int f = 0; f < 512; f += 4) {
        a0 += hroot[f + 0] * tof(fp[(size_t)(f + 0) * 256]);
        a1 += hroot[f + 1] * tof(fp[(size_t)(f + 1) * 256]);
        a2 += hroot[f + 2] * tof(fp[(size_t)(f + 2) * 256]);
        a3 += hroot[f + 3] * tof(fp[(size_t)(f + 3) * 256]);
    }
    store_val(outp + tid, (a0 + a1) + (a2 + a3));
}

__global__ __launch_bounds__(256) void gat_layer1(
    const float* h0_ws, const float* h1_ws, const void* w1, const void* a1s,
    const void* a1n, const void* fcw, void* out)
{
    const int b = blockIdx.x;
    const int tid = threadIdx.x;

    __shared__ float hs[11 * 516];
    __shared__ float xbar[4 * 512];
    __shared__ float attn[4][26];
    __shared__ float lsf[4];
    __shared__ float hroot[512];
    __shared__ int is_fp32;

    if (tid == 0) is_fp32 = detect_fp32(w1);
    __syncthreads();

    const float* h0row = h0_ws + (size_t)b * 512;
    const float* h1rows = h1_ws + (size_t)b * 10 * 512;
    if (!is_fp32)
        layer1_body<bf16>(h0row, h1rows, (const bf16*)w1, (const bf16*)a1s,
                          (const bf16*)a1n, (const bf16*)fcw,
                          (bf16*)out + (size_t)b * 256,
                          hs, xbar, attn, lsf, hroot, tid);
    else
        layer1_body<float>(h0row, h1rows, (const float*)w1, (const float*)a1s,
                           (const float*)a1n, (const float*)fcw,
                           (float*)out + (size_t)b * 256,
                           hs, xbar, attn, lsf, hroot, tid);
}

template <typename T>
__device__ __forceinline__ void gat_body(
    const T* x0, const T* x1, const T* x2, const T* w0, const T* a0s,
    const T* a0n, const T* w1, const T* a1s, const T* a1n, const T* fcw,
    T* out, float* xs, float* hs, float* xbar, float (*attn)[26],
    float* lsf, float* hroot, int b, int tid)
{
    for (int p = 0; p < 10; ++p) {
        const T* self  = x1 + ((size_t)b * 10 + p) * 256;
        const T* neigh = x2 + ((size_t)b * 250 + (size_t)p * 25) * 256;
        stage<T, 256, 26, 260>(xs, self, neigh, tid);
        __syncthreads();
        attention<T, 256, 26, 260>(xs, a0s, a0n, attn, lsf, tid);
        aggregate<256, 26, 260>(xs, attn, xbar, tid);
        __syncthreads();
        float2 r = transform_pair<T, 256>(xbar, w0, tid);
        int h = tid >> 6, d0 = (tid & 63) * 2;
        hs[(p + 1) * 516 + h * 128 + d0] = r.x;
        hs[(p + 1) * 516 + h * 128 + d0 + 1] = r.y;
        __syncthreads();
    }
    stage<T, 256, 11, 260>(xs, x0 + (size_t)b * 256, x1 + (size_t)b * 2560, tid);
    __syncthreads();
    attention<T, 256, 11, 260>(xs, a0s, a0n, attn, lsf, tid);
    aggregate<256, 11, 260>(xs, attn, xbar, tid);
    __syncthreads();
    {
        float2 r = transform_pair<T, 256>(xbar, w0, tid);
        int h = tid >> 6, d0 = (tid & 63) * 2;
        hs[h * 128 + d0] = r.x;
        hs[h * 128 + d0 + 1] = r.y;
    }
    __syncthreads();
    attention<T, 512, 11, 516>(hs, a1s, a1n, attn, lsf, tid);
    aggregate<512, 11, 516>(hs, attn, xbar, tid);
    __syncthreads();
    {
        float2 r = transform_pair<T, 512>(xbar, w1, tid);
        int h = tid >> 6, d0 = (tid & 63) * 2;
        hroot[h * 128 + d0] = r.x;
        hroot[h * 128 + d0 + 1] = r.y;
    }
    __syncthreads();
    const T* fp = fcw + tid;
    float a0 = 0.f, a1 = 0.f, a2 = 0.f, a3 = 0.f;
    for (int f = 0; f < 512; f += 4) {
        a0 += hroot[f + 0] * tof(fp[(size_t)(f + 0) * 256]);
        a1 += hroot[f + 1] * tof(fp[(size_t)(f + 1) * 256]);
        a2 += hroot[f + 2] * tof(fp[(size_t)(f + 2) * 256]);
        a3 += hroot[f + 3] * tof(fp[(size_t)(f + 3) * 256]);
    }
    store_val(&out[(size_t)b * 256 + tid], (a0 + a1) + (a2 + a3));
}

// only_if_fp32 = 1: run ONLY when inputs are fp32 (safety net beside the
// bf16 MFMA path); = 0: handle both dtypes (tier-2 fallback).
__global__ __launch_bounds__(256) void gat_fused(
    const void* x0, const void* x1, const void* x2, const void* w0,
    const void* a0s, const void* a0n, const void* w1, const void* a1s,
    const void* a1n, const void* fcw, void* out, int only_if_fp32)
{
    const int b = blockIdx.x;
    const int tid = threadIdx.x;

    __shared__ float xs[26 * 260];
    __shared__ float hs[11 * 516];
    __shared__ float xbar[4 * 512];
    __shared__ float attn[4][26];
    __shared__ float lsf[4];
    __shared__ float hroot[512];
    __shared__ int is_fp32;

    if (tid == 0) is_fp32 = detect_fp32(x0);
    __syncthreads();

    if (only_if_fp32 && !is_fp32) return;

    if (is_fp32)
        gat_body<float>((const float*)x0, (const float*)x1, (const float*)x2,
                        (const float*)w0, (const float*)a0s, (const float*)a0n,
                        (const float*)w1, (const float*)a1s, (const float*)a1n,
                        (const float*)fcw, (float*)out,
                        xs, hs, xbar, attn, lsf, hroot, b, tid);
    else
        gat_body<bf16>((const bf16*)x0, (const bf16*)x1, (const bf16*)x2,
                       (const bf16*)w0, (const bf16*)a0s, (const bf16*)a0n,
                       (const bf16*)w1, (const bf16*)a1s, (const bf16*)a1n,
                       (const bf16*)fcw, (bf16*)out,
                       xs, hs, xbar, attn, lsf, hroot, b, tid);
}

// =====================================================================
extern "C" void kernel_launch(void* const* d_in, const int* in_sizes, int n_in,
                              void* d_out, int out_size, void* d_ws, size_t ws_size,
                              hipStream_t stream) {
    const int B = in_sizes[0] / 256;   // 1024
    const int NB = 11 * B;             // 11264

    // ---- tier-0 workspace layout (bytes) ----
    size_t off = 0;
    const size_t o_wt0  = off; off += (size_t)4 * 128 * 256 * 2;   // 256 KB
    const size_t o_wt1  = off; off += (size_t)4 * 128 * 512 * 2;   // 512 KB
    const size_t o_fcwt = off; off += (size_t)256 * 512 * 2;       // 256 KB
    const size_t o_xb0  = off; off += (size_t)4 * NB * 256 * 2;    // 23.1 MB
    const size_t o_hall = off; off += (size_t)NB * 512 * 4;        // 23.1 MB (fp32)
    const size_t o_xb1  = off; off += (size_t)4 * B * 512 * 2;     // 4.2 MB
    const size_t o_hrt  = off; off += (size_t)B * 512 * 2;         // 1.0 MB
    const size_t need0 = off;
    const size_t need1 = (size_t)B * 512 * 4 + (size_t)B * 10 * 512 * 4;

    char* ws = (char*)d_ws;

    if (ws_size >= need0 && (B % 64) == 0) {
        bf16* wt0   = (bf16*)(ws + o_wt0);
        bf16* wt1   = (bf16*)(ws + o_wt1);
        bf16* fcwt  = (bf16*)(ws + o_fcwt);
        bf16* xbar0 = (bf16*)(ws + o_xb0);
        float* hall = (float*)(ws + o_hall);
        bf16* xbar1 = (bf16*)(ws + o_xb1);
        bf16* hroot = (bf16*)(ws + o_hrt);
        const bf16* probe = (const bf16*)d_in[3];  // w0

        transpose_weights<<<2048, 256, 0, stream>>>(
            (const bf16*)d_in[3], (const bf16*)d_in[6], (const bf16*)d_in[9],
            wt0, wt1, fcwt);
        gat_l0_attn<<<NB, 256, 0, stream>>>(
            (const bf16*)d_in[0], (const bf16*)d_in[1], (const bf16*)d_in[2],
            (const bf16*)d_in[4], (const bf16*)d_in[5], xbar0, B, NB);
        // h_all[n][512] (fp32) = per-head GEMM: xbar0_h[NB x 256] * wt0_h^T
        mfma_gemm<256><<<dim3(NB / 64, 1, 4), 256, 0, stream>>>(
            xbar0, wt0, hall, 0, (size_t)NB * 256, (size_t)128 * 256, 512, 128, probe);
        gat_l1_attn<<<B, 256, 0, stream>>>(
            hall, (const bf16*)d_in[7], (const bf16*)d_in[8], xbar1, B, probe);
        // hroot[b][512] (bf16) = per-head GEMM: xbar1_h[B x 512] * wt1_h^T
        mfma_gemm<512><<<dim3(B / 64, 1, 4), 256, 0, stream>>>(
            xbar1, wt1, hroot, 1, (size_t)B * 512, (size_t)128 * 512, 512, 128, probe);
        // out[b][256] (bf16) = hroot[B x 512] * fcwt^T
        mfma_gemm<512><<<dim3(B / 64, 2, 1), 256, 0, stream>>>(
            hroot, fcwt, d_out, 1, 0, 0, 256, 0, probe);
        // fp32 safety net (no-op when inputs are bf16)
        gat_fused<<<B, 256, 0, stream>>>(d_in[0], d_in[1], d_in[2], d_in[3], d_in[4],
                                         d_in[5], d_in[6], d_in[7], d_in[8], d_in[9],
                                         d_out, 1);
    } else if (ws_size >= need1) {
        float* h0_ws = (float*)d_ws;
        float* h1_ws = h0_ws + (size_t)B * 512;
        gat_layer0<<<B * 11, 256, 0, stream>>>(d_in[0], d_in[1], d_in[2], d_in[3],
                                               d_in[4], d_in[5], h0_ws, h1_ws, B);
        gat_layer1<<<B, 256, 0, stream>>>(h0_ws, h1_ws, d_in[6], d_in[7], d_in[8],
                                          d_in[9], d_out);
    } else {
        gat_fused<<<B, 256, 0, stream>>>(d_in[0], d_in[1], d_in[2], d_in[3], d_in[4],
                                         d_in[5], d_in[6], d_in[7], d_in[8], d_in[9],
                                         d_out, 0);
    }
}